// Round 8
// baseline (304.385 us; speedup 1.0000x reference)
//
#include <hip/hip_runtime.h>
#include <hip/hip_bf16.h>

#define NN 100000
#define NE 600000
#define DD 128
#define NL 3
#define NG 64
#define LN_EPS 1e-5f

typedef __attribute__((ext_vector_type(8))) short short8v;
typedef __attribute__((ext_vector_type(8))) unsigned short ushort8v;
typedef __attribute__((ext_vector_type(4))) float f32x4;
typedef unsigned short ushort;
typedef unsigned int uint;

// unpack dword of 2 bf16 (cols c, c+1) to fp32
__device__ inline float2 unpk2(uint u) {
  float2 r;
  r.x = __uint_as_float(u << 16);
  r.y = __uint_as_float(u & 0xffff0000u);
  return r;
}

// split fp32 pair -> (hi bf16 pair, lo bf16 pair); hi = truncate, lo = RNE(residual)
__device__ inline void split2(float ax, float ay, uint& hi2, uint& lo2) {
  const uint ux = __float_as_uint(ax), uy = __float_as_uint(ay);
  hi2 = (ux >> 16) | (uy & 0xffff0000u);
  const float rx = ax - __uint_as_float(ux & 0xffff0000u);
  const float ry = ay - __uint_as_float(uy & 0xffff0000u);
  __hip_bfloat16 bx = __float2bfloat16(rx), by = __float2bfloat16(ry);
  lo2 = (uint)*(ushort*)&bx | ((uint)*(ushort*)&by << 16);
}

// ============ CSR build ============
__global__ __launch_bounds__(256)
void count_kernel(const int* __restrict__ dst, int* __restrict__ deg) {
  const int e = blockIdx.x * 256 + threadIdx.x;
  if (e < NE) atomicAdd(&deg[dst[e]], 1);
}

__global__ __launch_bounds__(256)
void scan_a(const int* __restrict__ deg, int* __restrict__ off, int* __restrict__ btot) {
  __shared__ int wsum[4];
  const int t = threadIdx.x, lane = t & 63, wid = t >> 6;
  const int base = blockIdx.x * 1024 + t * 4;
  int4 d = {0, 0, 0, 0};
  if (base < NN) d = *(const int4*)(deg + base);
  const int s0 = d.x, s1 = s0 + d.y, s2 = s1 + d.z, s3 = s2 + d.w;
  int v = s3;
#pragma unroll
  for (int o = 1; o < 64; o <<= 1) { const int u = __shfl_up(v, o); if (lane >= o) v += u; }
  if (lane == 63) wsum[wid] = v;
  __syncthreads();
  if (t == 0) {
    int a = 0;
#pragma unroll
    for (int i = 0; i < 4; ++i) { const int x = wsum[i]; wsum[i] = a; a += x; }
    btot[blockIdx.x] = a;
  }
  __syncthreads();
  const int texcl = wsum[wid] + v - s3;
  if (base < NN) {
    const int4 o4 = {texcl, texcl + s0, texcl + s1, texcl + s2};
    *(int4*)(off + base) = o4;
  }
}

__global__ __launch_bounds__(128)
void scan_b(int* __restrict__ btot, int nb) {
  __shared__ int wsum[2];
  const int t = threadIdx.x, lane = t & 63, wid = t >> 6;
  const int x = (t < nb) ? btot[t] : 0;
  int v = x;
#pragma unroll
  for (int o = 1; o < 64; o <<= 1) { const int u = __shfl_up(v, o); if (lane >= o) v += u; }
  if (lane == 63) wsum[wid] = v;
  __syncthreads();
  if (t == 0) { const int w0 = wsum[0]; wsum[0] = 0; wsum[1] = w0; }
  __syncthreads();
  const int excl = wsum[wid] + v - x;
  if (t < nb) btot[t] = excl;
}

__global__ __launch_bounds__(256)
void scan_c(int* __restrict__ off, const int* __restrict__ btot) {
  const int i = blockIdx.x * 256 + threadIdx.x;
  if (i < NN) off[i] += btot[i >> 10];
}

// fill: atomicAdd turns off[] starts into ends; csr = src per dst bucket
__global__ __launch_bounds__(256)
void fill_kernel(const int* __restrict__ src, const int* __restrict__ dst,
                 int* __restrict__ off, int* __restrict__ csr) {
  const int e = blockIdx.x * 256 + threadIdx.x;
  if (e < NE) {
    const int p = atomicAdd(&off[dst[e]], 1);
    csr[p] = src[e];
  }
}

// ELL: per node 10 ints — [0..7] padded neighbor ids (NN if empty),
// [8] = csr row start, [9] = degree. Built AFTER fill (off[] holds ends).
__global__ __launch_bounds__(256)
void ell_kernel(const int* __restrict__ off, const int* __restrict__ csr,
                int* __restrict__ ell) {
  const int v = blockIdx.x * 256 + threadIdx.x;
  if (v >= NN) return;
  const int i0 = v ? off[v - 1] : 0;
  const int i1 = off[v];
  const int dg = i1 - i0;
  int* ep = ell + v * 10;
#pragma unroll
  for (int s = 0; s < 8; ++s) ep[s] = (s < dg) ? csr[i0 + s] : NN;
  ep[8] = i0;
  ep[9] = dg;
}

// ============ weight prep: fragment-ordered bf16 hi/lo ============
__global__ __launch_bounds__(256)
void wprep_kernel(const float* __restrict__ projW, const float* __restrict__ mlpW,
                  ushort* __restrict__ Wp) {
  const int tid = blockIdx.x * 256 + threadIdx.x;   // 8192 total
  const int lane = tid & 63;
  const int fid = tid >> 6;                         // 0..127
  const int mat = fid >> 5;
  const int rem = fid & 31;
  const int kk = rem >> 3, nf = rem & 7;
  const float* W = (mat == 0) ? projW : (mlpW + (size_t)(mat - 1) * DD * DD);
  const int k0 = kk * 32 + (lane >> 4) * 8;
  const int col = nf * 16 + (lane & 15);
  ushort8v hv, lv;
#pragma unroll
  for (int j = 0; j < 8; ++j) {
    const float f = W[(size_t)(k0 + j) * DD + col];
    __hip_bfloat16 bh = __float2bfloat16(f);
    __hip_bfloat16 bl = __float2bfloat16(f - __bfloat162float(bh));
    hv[j] = *(ushort*)&bh;
    lv[j] = *(ushort*)&bl;
  }
  ushort* base = Wp + (size_t)mat * 32768;
  *(ushort8v*)(base + ((size_t)((kk * 8 + nf) * 2 + 0) * 64 + lane) * 8) = hv;
  *(ushort8v*)(base + ((size_t)((kk * 8 + nf) * 2 + 1) * 64 + lane) * 8) = lv;
}

// ============ fused [flat ELL gather +] GEMM + ReLU [+ LN] ============
// Block 256, tile 64 rows x 128 cols. STAGING (flat, max ILP):
//   quarter-wave qw = t>>4 owns rows {qw, qw+16, qw+32, qw+48}; lane ll
//   covers cols 8ll..8ll+7. 36 INDEPENDENT gathers (4 rows x (8 ELL slots
//   + self)) issued in 6 groups of 6, depth-2 rotation. Indices from one
//   int2 ELL load + width-16 shuffles. deg>8 tails: rare serial loop.
// One barrier; MFMA: wave w owns rows w*16..+15 (R6 scheme), B dbuf'd
// across the 32 flattened (kk,nf) steps. LN per-wave (16-lane shuffle).
template<int MODE>
__global__ __launch_bounds__(256, 4)
void gemm_node(const float* __restrict__ Xf, const ushort* __restrict__ Hin,
               const int* __restrict__ ell, const int* __restrict__ csr,
               const ushort* __restrict__ Wp, const float* __restrict__ bias,
               const float* __restrict__ lng, const float* __restrict__ lnb,
               ushort* __restrict__ Hout) {
  __align__(16) __shared__ ushort AH[64 * 128];
  __align__(16) __shared__ ushort AL[64 * 128];
  const int t = threadIdx.x, lane = t & 63, w = t >> 6;
  const int r0 = blockIdx.x * 64;

  if constexpr (MODE == 1) {
    const int qw = t >> 4, ll = t & 15;
    const uint4* __restrict__ hu4 = (const uint4*)Hin;
    // ---- ELL index preload: lane ll covers (k=ll>>2, slots (ll&3)*2,+1) ----
    int2 e = {NN, NN};
    int2 e2 = {0, 0};   // {i0, deg} for row k=ll>>2 (valid on ll&3==0)
    {
      const int gr_l = r0 + qw + 16 * (ll >> 2);
      if (gr_l < NN) {
        e = *(const int2*)&ell[gr_l * 10 + (ll & 3) * 2];
        if ((ll & 3) == 0) e2 = *(const int2*)&ell[gr_l * 10 + 8];
      }
    }
    // task = s*4+k, s in 0..8 (s==8 -> self), k in 0..3
    float a[4][8];
#pragma unroll
    for (int k = 0; k < 4; ++k)
#pragma unroll
      for (int j = 0; j < 8; ++j) a[k][j] = 0.f;

    uint4 gA[6], gB[6];
    auto IDX = [&](int k, int s) -> int {
      if (s == 8) { const int gr = r0 + qw + 16 * k; return gr < NN ? gr : NN; }
      const int src = (k << 2) + (s >> 1);
      const int ex = __shfl(e.x, src, 16);
      const int ey = __shfl(e.y, src, 16);
      return (s & 1) ? ey : ex;
    };
    auto ISSUE = [&](int g, uint4 (&gb)[6]) {
#pragma unroll
      for (int m = 0; m < 6; ++m) {
        const int task = g * 6 + m;
        const int id = IDX(task & 3, task >> 2);
        gb[m] = hu4[id * 16 + ll];
      }
    };
    auto CONS = [&](int g, uint4 (&gb)[6]) {
#pragma unroll
      for (int m = 0; m < 6; ++m) {
        const int k = (g * 6 + m) & 3;
        const float2 p0 = unpk2(gb[m].x), p1 = unpk2(gb[m].y);
        const float2 p2 = unpk2(gb[m].z), p3 = unpk2(gb[m].w);
        a[k][0] += p0.x; a[k][1] += p0.y;
        a[k][2] += p1.x; a[k][3] += p1.y;
        a[k][4] += p2.x; a[k][5] += p2.y;
        a[k][6] += p3.x; a[k][7] += p3.y;
      }
    };
    ISSUE(0, gA); ISSUE(1, gB);
    CONS(0, gA);  ISSUE(2, gA);
    CONS(1, gB);  ISSUE(3, gB);
    CONS(2, gA);  ISSUE(4, gA);
    CONS(3, gB);  ISSUE(5, gB);
    CONS(4, gA);  CONS(5, gB);

    // ---- rare tails (deg > 8), uniform per 16-lane group ----
#pragma unroll
    for (int k = 0; k < 4; ++k) {
      const int i0k = __shfl(e2.x, k << 2, 16);
      const int dgk = __shfl(e2.y, k << 2, 16);
      if (dgk > 8) {
        const int end = i0k + dgk;
#pragma unroll 1
        for (int i = i0k + 8; i < end; i += 2) {
          const int ia = csr[i];
          const int ibr = i + 1 < end ? csr[i + 1] : NN;
          const uint4 ga = hu4[ia * 16 + ll];
          const uint4 gb_ = hu4[ibr * 16 + ll];
          const float2 q0 = unpk2(ga.x), q1 = unpk2(ga.y), q2 = unpk2(ga.z), q3 = unpk2(ga.w);
          const float2 r0_ = unpk2(gb_.x), r1 = unpk2(gb_.y), r2 = unpk2(gb_.z), r3 = unpk2(gb_.w);
          a[k][0] += q0.x + r0_.x; a[k][1] += q0.y + r0_.y;
          a[k][2] += q1.x + r1.x;  a[k][3] += q1.y + r1.y;
          a[k][4] += q2.x + r2.x;  a[k][5] += q2.y + r2.y;
          a[k][6] += q3.x + r3.x;  a[k][7] += q3.y + r3.y;
        }
      }
    }

    // ---- split + LDS write ----
#pragma unroll
    for (int k = 0; k < 4; ++k) {
      uint h0, l0, h1, l1, h2, l2, h3, l3;
      split2(a[k][0], a[k][1], h0, l0);
      split2(a[k][2], a[k][3], h1, l1);
      split2(a[k][4], a[k][5], h2, l2);
      split2(a[k][6], a[k][7], h3, l3);
      const int row = qw + 16 * k;
      const int uoff = (row * 16 + (ll ^ (row & 7))) * 8;
      *(uint4*)&AH[uoff] = make_uint4(h0, h1, h2, h3);
      *(uint4*)&AL[uoff] = make_uint4(l0, l1, l2, l3);
    }
  } else {
    // ---- MODE 0: flat one-shot (thread t: row t>>2, 32 cols) ----
    const int row = t >> 2;
    const int c = t & 3;
    int v = r0 + row;
    v = v < NN ? v : NN - 1;            // clamp; masked rows never stored
    const float4* __restrict__ Xf4 = (const float4*)Xf;
    float4 fa[4], fb[4];
#pragma unroll
    for (int m = 0; m < 4; ++m) {
      fa[m] = Xf4[v * 32 + c * 8 + 2 * m];
      fb[m] = Xf4[v * 32 + c * 8 + 2 * m + 1];
    }
#pragma unroll
    for (int m = 0; m < 4; ++m) {
      uint h0, l0, h1, l1, h2, l2, h3, l3;
      split2(fa[m].x, fa[m].y, h0, l0);
      split2(fa[m].z, fa[m].w, h1, l1);
      split2(fb[m].x, fb[m].y, h2, l2);
      split2(fb[m].z, fb[m].w, h3, l3);
      const int llv = c * 4 + m;
      const int uoff = (row * 16 + (llv ^ (row & 7))) * 8;
      *(uint4*)&AH[uoff] = make_uint4(h0, h1, h2, h3);
      *(uint4*)&AL[uoff] = make_uint4(l0, l1, l2, l3);
    }
  }
  __syncthreads();

  // ---- MFMA: wave w -> rows w*16..+15; B dbuf across 32 steps ----
  f32x4 accv[8];
#pragma unroll
  for (int nf = 0; nf < 8; ++nf) accv[nf] = (f32x4){0.f, 0.f, 0.f, 0.f};
  const int arow = w * 16 + (lane & 15);
  const int q = lane >> 4;
  const int rx = arow & 7;

  short8v bh[2], bl[2];
  {
    const ushort* bp = Wp + ((size_t)0 * 64 + lane) * 8;
    bh[0] = *(const short8v*)bp;
    bl[0] = *(const short8v*)(bp + 512);
  }
  short8v ah{}, al{};
#pragma unroll
  for (int st = 0; st < 32; ++st) {
    if (st < 31) {
      const ushort* bp = Wp + ((size_t)((st + 1) * 2) * 64 + lane) * 8;
      bh[(st + 1) & 1] = *(const short8v*)bp;
      bl[(st + 1) & 1] = *(const short8v*)(bp + 512);
    }
    const int kk = st >> 3, nf = st & 7;
    if (nf == 0) {
      const int aidx = (arow * 16 + ((kk * 4 + q) ^ rx)) * 8;
      ah = *(const short8v*)&AH[aidx];
      al = *(const short8v*)&AL[aidx];
    }
    accv[nf] = __builtin_amdgcn_mfma_f32_16x16x32_bf16(ah, bh[st & 1], accv[nf], 0, 0, 0);
    accv[nf] = __builtin_amdgcn_mfma_f32_16x16x32_bf16(al, bh[st & 1], accv[nf], 0, 0, 0);
    accv[nf] = __builtin_amdgcn_mfma_f32_16x16x32_bf16(ah, bl[st & 1], accv[nf], 0, 0, 0);
  }

  // ---- epilogue: bias + ReLU [+ LN], store bf16 ----
  const int colb = lane & 15;
  float bias8[8], g8[8], q8[8];
#pragma unroll
  for (int nf = 0; nf < 8; ++nf) {
    bias8[nf] = bias[nf * 16 + colb];
    if (MODE == 1) { g8[nf] = lng[nf * 16 + colb]; q8[nf] = lnb[nf * 16 + colb]; }
  }
#pragma unroll
  for (int r = 0; r < 4; ++r) {
    const int grow = r0 + w * 16 + (lane >> 4) * 4 + r;
    float z[8];
    float s = 0.f, s2 = 0.f;
#pragma unroll
    for (int nf = 0; nf < 8; ++nf) {
      z[nf] = fmaxf(accv[nf][r] + bias8[nf], 0.f);
      s += z[nf];
      s2 += z[nf] * z[nf];
    }
    if (MODE == 1) {
#pragma unroll
      for (int o = 1; o < 16; o <<= 1) { s += __shfl_xor(s, o); s2 += __shfl_xor(s2, o); }
      const float mu = s * (1.f / DD);
      const float inv = rsqrtf(s2 * (1.f / DD) - mu * mu + LN_EPS);
#pragma unroll
      for (int nf = 0; nf < 8; ++nf) z[nf] = (z[nf] - mu) * inv * g8[nf] + q8[nf];
    }
    if (grow < NN) {
      ushort* yp = Hout + grow * DD + colb;
#pragma unroll
      for (int nf = 0; nf < 8; ++nf) {
        __hip_bfloat16 b = __float2bfloat16(z[nf]);
        yp[nf * 16] = *(ushort*)&b;
      }
    }
  }
}

// ============ pool (bf16 h, batch_ids sorted; 64 threads, uint loads) ============
__global__ __launch_bounds__(64)
void pool_kernel(const ushort* __restrict__ h, const int* __restrict__ batch,
                 float* __restrict__ sums, float* __restrict__ counts) {
  const int c = threadIdx.x;                 // uint index: cols 2c, 2c+1
  const int base = blockIdx.x * 64;
  const int end = (base + 64 < NN) ? base + 64 : NN;
  const uint* __restrict__ hu = (const uint*)h;
  int cur = batch[base];
  float a0 = 0.f, a1 = 0.f, cnt = 0.f;
  for (int r = base; r < end; ++r) {
    const int g = batch[r];
    if (g != cur) {
      __hip_atomic_fetch_add(&sums[cur * DD + 2 * c], a0, __ATOMIC_RELAXED, __HIP_MEMORY_SCOPE_AGENT);
      __hip_atomic_fetch_add(&sums[cur * DD + 2 * c + 1], a1, __ATOMIC_RELAXED, __HIP_MEMORY_SCOPE_AGENT);
      if (c == 0)
        __hip_atomic_fetch_add(&counts[cur], cnt, __ATOMIC_RELAXED, __HIP_MEMORY_SCOPE_AGENT);
      a0 = 0.f; a1 = 0.f; cnt = 0.f; cur = g;
    }
    const float2 f = unpk2(hu[r * 64 + c]);
    a0 += f.x; a1 += f.y; cnt += 1.f;
  }
  __hip_atomic_fetch_add(&sums[cur * DD + 2 * c], a0, __ATOMIC_RELAXED, __HIP_MEMORY_SCOPE_AGENT);
  __hip_atomic_fetch_add(&sums[cur * DD + 2 * c + 1], a1, __ATOMIC_RELAXED, __HIP_MEMORY_SCOPE_AGENT);
  if (c == 0)
    __hip_atomic_fetch_add(&counts[cur], cnt, __ATOMIC_RELAXED, __HIP_MEMORY_SCOPE_AGENT);
}

__global__ __launch_bounds__(256)
void finalize_kernel(const float* __restrict__ sums, const float* __restrict__ counts,
                     float* __restrict__ out) {
  const int i = blockIdx.x * 256 + threadIdx.x;
  if (i >= NG * DD) return;
  out[i] = sums[i] / fmaxf(counts[i >> 7], 1.f);
}

extern "C" void kernel_launch(void* const* d_in, const int* in_sizes, int n_in,
                              void* d_out, int out_size, void* d_ws, size_t ws_size,
                              hipStream_t stream) {
  const float* x     = (const float*)d_in[0];
  const int*   ei    = (const int*)d_in[1];
  const int*   batch = (const int*)d_in[2];
  const float* projW = (const float*)d_in[3];
  const float* projb = (const float*)d_in[4];
  const float* mlpW  = (const float*)d_in[5];
  const float* mlpb  = (const float*)d_in[6];
  const float* lng   = (const float*)d_in[7];
  const float* lnb   = (const float*)d_in[8];
  float* out = (float*)d_out;

  char* ws = (char*)d_ws;
  ushort* hA    = (ushort*)(ws + 0);           // (NN+1)*256 B = 25,600,256
  ushort* hB    = (ushort*)(ws + 25600256);    // 25,600,256 B
  int*   csr    = (int*)   (ws + 51200512);    //  2,400,000 B
  int*   ell    = (int*)   (ws + 53600512);    //  4,000,000 B
  int*   deg    = (int*)   (ws + 57600512);    //    400,000 B
  int*   off    = (int*)   (ws + 58000512);    //    400,000 B
  int*   btot   = (int*)   (ws + 58400512);    //        512 B
  ushort* Wp    = (ushort*)(ws + 58401024);    //    262,144 B
  float* sums   = (float*) (ws + 58663168);    //     32,768 B
  float* counts = (float*) (ws + 58695936);    //        256 B

  const int* src = ei;
  const int* dst = ei + NE;

  // zero rows (index NN) for the gather zero-target
  hipMemsetAsync(hA + (size_t)NN * DD, 0, DD * sizeof(ushort), stream);
  hipMemsetAsync(hB + (size_t)NN * DD, 0, DD * sizeof(ushort), stream);

  // ---- CSR + ELL build ----
  hipMemsetAsync(deg, 0, NN * sizeof(int), stream);
  count_kernel<<<(NE + 255) / 256, 256, 0, stream>>>(dst, deg);
  scan_a<<<(NN + 1023) / 1024, 256, 0, stream>>>(deg, off, btot);
  scan_b<<<1, 128, 0, stream>>>(btot, (NN + 1023) / 1024);
  scan_c<<<(NN + 255) / 256, 256, 0, stream>>>(off, btot);
  fill_kernel<<<(NE + 255) / 256, 256, 0, stream>>>(src, dst, off, csr);
  ell_kernel<<<(NN + 255) / 256, 256, 0, stream>>>(off, csr, ell);

  // ---- weight prep ----
  wprep_kernel<<<32, 256, 0, stream>>>(projW, mlpW, Wp);

  const int gemm_blocks = (NN + 63) / 64;   // 1563

  // h = relu(x @ projW + projb) -> bf16
  gemm_node<0><<<gemm_blocks, 256, 0, stream>>>(
      x, nullptr, nullptr, nullptr, Wp, projb, nullptr, nullptr, hA);

  // 3 fused GIN layers, ping-pong hA/hB
  ushort* hin = hA;
  ushort* hout = hB;
  for (int l = 0; l < NL; ++l) {
    gemm_node<1><<<gemm_blocks, 256, 0, stream>>>(
        nullptr, hin, ell, csr, Wp + (size_t)(1 + l) * 32768,
        mlpb + (size_t)l * DD, lng + (size_t)l * DD, lnb + (size_t)l * DD, hout);
    ushort* tmp = hin; hin = hout; hout = tmp;
  }

  hipMemsetAsync(sums, 0, (size_t)(NG * DD + NG) * sizeof(float), stream);
  pool_kernel<<<(NN + 63) / 64, 64, 0, stream>>>(hin, batch, sums, counts);
  finalize_kernel<<<(NG * DD + 255) / 256, 256, 0, stream>>>(sums, counts, out);
}

// Round 10
// 274.783 us; speedup vs baseline: 1.1077x; 1.1077x over previous
//
#include <hip/hip_runtime.h>
#include <hip/hip_bf16.h>

#define NN 100000
#define NE 600000
#define DD 128
#define NL 3
#define NG 64
#define LN_EPS 1e-5f

typedef __attribute__((ext_vector_type(8))) short short8v;
typedef __attribute__((ext_vector_type(8))) unsigned short ushort8v;
typedef __attribute__((ext_vector_type(4))) float f32x4;
typedef unsigned short ushort;
typedef unsigned int uint;

// unpack dword of 2 bf16 (cols c, c+1) to fp32
__device__ inline float2 unpk2(uint u) {
  float2 r;
  r.x = __uint_as_float(u << 16);
  r.y = __uint_as_float(u & 0xffff0000u);
  return r;
}

// split fp32 pair -> (hi bf16 pair, lo bf16 pair); hi = truncate, lo = RNE(residual)
__device__ inline void split2(float ax, float ay, uint& hi2, uint& lo2) {
  const uint ux = __float_as_uint(ax), uy = __float_as_uint(ay);
  hi2 = (ux >> 16) | (uy & 0xffff0000u);
  const float rx = ax - __uint_as_float(ux & 0xffff0000u);
  const float ry = ay - __uint_as_float(uy & 0xffff0000u);
  __hip_bfloat16 bx = __float2bfloat16(rx), by = __float2bfloat16(ry);
  lo2 = (uint)*(ushort*)&bx | ((uint)*(ushort*)&by << 16);
}

// RNE pack of two fp32 -> dword of 2 bf16
__device__ inline uint pack2(float a, float b) {
  __hip_bfloat16 ba = __float2bfloat16(a), bb = __float2bfloat16(b);
  return (uint)*(ushort*)&ba | ((uint)*(ushort*)&bb << 16);
}

// ============ CSR build ============
__global__ __launch_bounds__(256)
void count_kernel(const int* __restrict__ dst, int* __restrict__ deg) {
  const int e = blockIdx.x * 256 + threadIdx.x;
  if (e < NE) atomicAdd(&deg[dst[e]], 1);
}

__global__ __launch_bounds__(256)
void scan_a(const int* __restrict__ deg, int* __restrict__ off, int* __restrict__ btot) {
  __shared__ int wsum[4];
  const int t = threadIdx.x, lane = t & 63, wid = t >> 6;
  const int base = blockIdx.x * 1024 + t * 4;
  int4 d = {0, 0, 0, 0};
  if (base < NN) d = *(const int4*)(deg + base);
  const int s0 = d.x, s1 = s0 + d.y, s2 = s1 + d.z, s3 = s2 + d.w;
  int v = s3;
#pragma unroll
  for (int o = 1; o < 64; o <<= 1) { const int u = __shfl_up(v, o); if (lane >= o) v += u; }
  if (lane == 63) wsum[wid] = v;
  __syncthreads();
  if (t == 0) {
    int a = 0;
#pragma unroll
    for (int i = 0; i < 4; ++i) { const int x = wsum[i]; wsum[i] = a; a += x; }
    btot[blockIdx.x] = a;
  }
  __syncthreads();
  const int texcl = wsum[wid] + v - s3;
  if (base < NN) {
    const int4 o4 = {texcl, texcl + s0, texcl + s1, texcl + s2};
    *(int4*)(off + base) = o4;
  }
}

__global__ __launch_bounds__(128)
void scan_b(int* __restrict__ btot, int nb) {
  __shared__ int wsum[2];
  const int t = threadIdx.x, lane = t & 63, wid = t >> 6;
  const int x = (t < nb) ? btot[t] : 0;
  int v = x;
#pragma unroll
  for (int o = 1; o < 64; o <<= 1) { const int u = __shfl_up(v, o); if (lane >= o) v += u; }
  if (lane == 63) wsum[wid] = v;
  __syncthreads();
  if (t == 0) { const int w0 = wsum[0]; wsum[0] = 0; wsum[1] = w0; }
  __syncthreads();
  const int excl = wsum[wid] + v - x;
  if (t < nb) btot[t] = excl;
}

__global__ __launch_bounds__(256)
void scan_c(int* __restrict__ off, const int* __restrict__ btot) {
  const int i = blockIdx.x * 256 + threadIdx.x;
  if (i < NN) off[i] += btot[i >> 10];
}

// fill: atomicAdd turns off[] starts into ends; csr = src per dst bucket
__global__ __launch_bounds__(256)
void fill_kernel(const int* __restrict__ src, const int* __restrict__ dst,
                 int* __restrict__ off, int* __restrict__ csr) {
  const int e = blockIdx.x * 256 + threadIdx.x;
  if (e < NE) {
    const int p = atomicAdd(&off[dst[e]], 1);
    csr[p] = src[e];
  }
}

// ============ weight prep: fragment-ordered bf16 hi/lo ============
__global__ __launch_bounds__(256)
void wprep_kernel(const float* __restrict__ projW, const float* __restrict__ mlpW,
                  ushort* __restrict__ Wp) {
  const int tid = blockIdx.x * 256 + threadIdx.x;   // 8192 total
  const int lane = tid & 63;
  const int fid = tid >> 6;                         // 0..127
  const int mat = fid >> 5;
  const int rem = fid & 31;
  const int kk = rem >> 3, nf = rem & 7;
  const float* W = (mat == 0) ? projW : (mlpW + (size_t)(mat - 1) * DD * DD);
  const int k0 = kk * 32 + (lane >> 4) * 8;
  const int col = nf * 16 + (lane & 15);
  ushort8v hv, lv;
#pragma unroll
  for (int j = 0; j < 8; ++j) {
    const float f = W[(size_t)(k0 + j) * DD + col];
    __hip_bfloat16 bh = __float2bfloat16(f);
    __hip_bfloat16 bl = __float2bfloat16(f - __bfloat162float(bh));
    hv[j] = *(ushort*)&bh;
    lv[j] = *(ushort*)&bl;
  }
  ushort* base = Wp + (size_t)mat * 32768;
  *(ushort8v*)(base + ((size_t)((kk * 8 + nf) * 2 + 0) * 64 + lane) * 8) = hv;
  *(ushort8v*)(base + ((size_t)((kk * 8 + nf) * 2 + 1) * 64 + lane) * 8) = lv;
}

// ============ fused [gather-sum +] GEMM + ReLU [+ LN] ============
// Block 256 = 4 waves, tile 64 rows x 128 cols. Wave w owns rows w*16..+15
// end-to-end (staging, MFMA, epilogue) — NO barriers, all LDS wave-private.
// Staging: R6 quarter-wave depth-2 pipeline (best measured).
// Epilogue: bias+ReLU[+LN] in regs -> bf16-pair pack (2 shuffles per j,
//   lane-uniform nf) -> swizzled wave-private LDS transpose -> COALESCED
//   global_store_dwordx4 (1 KB contiguous per wave instruction).
template<int MODE>
__global__ __launch_bounds__(256, 4)
void gemm_node(const float* __restrict__ Xf, const ushort* __restrict__ Hin,
               const int* __restrict__ csr, const int* __restrict__ offE,
               const ushort* __restrict__ Wp, const float* __restrict__ bias,
               const float* __restrict__ lng, const float* __restrict__ lnb,
               ushort* __restrict__ Hout) {
  __align__(16) __shared__ ushort AH[64 * 128];
  __align__(16) __shared__ ushort AL[64 * 128];
  const int t = threadIdx.x, lane = t & 63, w = t >> 6;
  const int q = lane >> 4;          // quarter 0..3
  const int ll = lane & 15;         // chunk index within row
  const int r0 = blockIdx.x * 64;
  const int qbase = r0 + w * 16 + q * 4;   // first staged row of this quarter
  const uint4* __restrict__ hu4 = (const uint4*)Hin;

  // ================= staging (R6 scheme) =================
  if constexpr (MODE == 1) {
    int offv = 0;
    if (ll < 5) {
      const int gi = qbase - 1 + ll;
      const int gic = gi < 0 ? 0 : (gi > NN - 1 ? NN - 1 : gi);
      offv = (gi < 0) ? 0 : offE[gic];
    }
    int idxA, idxB;
    {
      const int j = ll & 7;
      const int rA = ll >> 3;
      const int a0 = __shfl(offv, q * 16 + rA);
      const int a1 = __shfl(offv, q * 16 + rA + 1);
      int ii = a0 + j;
      int iic = ii < NE ? ii : NE - 1;
      const int cv = csr[iic];
      idxA = (ii < a1) ? cv : NN;
      const int rB = 2 + (ll >> 3);
      const int b0 = __shfl(offv, q * 16 + rB);
      const int b1 = __shfl(offv, q * 16 + rB + 1);
      ii = b0 + j;
      iic = ii < NE ? ii : NE - 1;
      const int cw = csr[iic];
      idxB = (ii < b1) ? cw : NN;
    }

    uint4 gA[9], gB[9];
    auto ISSUE = [&](int s, uint4 (&g)[9]) {
      const int bl = q * 16 + ((s & 1) << 3);
      const int srcv = (s < 2) ? idxA : idxB;
#pragma unroll
      for (int j = 0; j < 8; ++j) {
        const int id = __shfl(srcv, bl + j);
        g[j] = hu4[id * 16 + ll];
      }
      const int v = qbase + s;
      const int sid = (v < NN) ? v : NN;
      g[8] = hu4[sid * 16 + ll];
    };
    auto CONSUME = [&](int s, uint4 (&g)[9]) {
      float4 ev = {0.f, 0.f, 0.f, 0.f}, od = {0.f, 0.f, 0.f, 0.f};
#pragma unroll
      for (int j = 0; j < 9; ++j) {
        const float2 a = unpk2(g[j].x), b = unpk2(g[j].y);
        const float2 c = unpk2(g[j].z), d = unpk2(g[j].w);
        ev.x += a.x; od.x += a.y; ev.y += b.x; od.y += b.y;
        ev.z += c.x; od.z += c.y; ev.w += d.x; od.w += d.y;
      }
      const int i0s = __shfl(offv, q * 16 + s);
      const int i1s = __shfl(offv, q * 16 + s + 1);
      int i = i0s + 8;
#pragma unroll 1
      while (i < i1s) {
#pragma unroll
        for (int jj = 0; jj < 4; ++jj) {
          const int ii = i + jj;
          const int iic = ii < NE ? ii : NE - 1;
          int id = csr[iic];
          id = (ii < i1s) ? id : NN;
          const uint4 gg = hu4[id * 16 + ll];
          const float2 a = unpk2(gg.x), b = unpk2(gg.y);
          const float2 c = unpk2(gg.z), d = unpk2(gg.w);
          ev.x += a.x; od.x += a.y; ev.y += b.x; od.y += b.y;
          ev.z += c.x; od.z += c.y; ev.w += d.x; od.w += d.y;
        }
        i += 4;
      }
      uint h0, l0, h1, l1, h2, l2, h3, l3;
      split2(ev.x, od.x, h0, l0);
      split2(ev.y, od.y, h1, l1);
      split2(ev.z, od.z, h2, l2);
      split2(ev.w, od.w, h3, l3);
      const int row = w * 16 + q * 4 + s;
      const int uoff = (row * 16 + (ll ^ (row & 7))) * 8;
      *(uint4*)&AH[uoff] = make_uint4(h0, h1, h2, h3);
      *(uint4*)&AL[uoff] = make_uint4(l0, l1, l2, l3);
    };

    ISSUE(0, gA);
    ISSUE(1, gB);
    CONSUME(0, gA);
    ISSUE(2, gA);
    CONSUME(1, gB);
    ISSUE(3, gB);
    CONSUME(2, gA);
    CONSUME(3, gB);
  } else {
    const float4* __restrict__ Xf4 = (const float4*)Xf;
    float4 a0, b0, a1, b1;
    auto LOADX = [&](int s, float4& fa, float4& fb) {
      int v = qbase + s;
      v = v < NN ? v : NN - 1;        // clamp; masked rows never stored
      fa = Xf4[v * 32 + 2 * ll];
      fb = Xf4[v * 32 + 2 * ll + 1];
    };
    auto STOREX = [&](int s, const float4& fa, const float4& fb) {
      uint h0, l0, h1, l1, h2, l2, h3, l3;
      split2(fa.x, fa.y, h0, l0);
      split2(fa.z, fa.w, h1, l1);
      split2(fb.x, fb.y, h2, l2);
      split2(fb.z, fb.w, h3, l3);
      const int row = w * 16 + q * 4 + s;
      const int uoff = (row * 16 + (ll ^ (row & 7))) * 8;
      *(uint4*)&AH[uoff] = make_uint4(h0, h1, h2, h3);
      *(uint4*)&AL[uoff] = make_uint4(l0, l1, l2, l3);
    };
    LOADX(0, a0, b0);
    LOADX(1, a1, b1);
    STOREX(0, a0, b0);
    LOADX(2, a0, b0);
    STOREX(1, a1, b1);
    LOADX(3, a1, b1);
    STOREX(2, a0, b0);
    STOREX(3, a1, b1);
  }
  // no barrier: each wave reads only its own staged rows below

  // ================= MFMA (R6 scheme) =================
  f32x4 accv[8];
#pragma unroll
  for (int nf = 0; nf < 8; ++nf) accv[nf] = (f32x4){0.f, 0.f, 0.f, 0.f};
  const int arow = w * 16 + (lane & 15);
  const int rx = arow & 7;
#pragma unroll
  for (int kk = 0; kk < 4; ++kk) {
    const int aidx = (arow * 16 + ((kk * 4 + q) ^ rx)) * 8;
    const short8v ah = *(const short8v*)&AH[aidx];
    const short8v al = *(const short8v*)&AL[aidx];
#pragma unroll
    for (int nf = 0; nf < 8; ++nf) {
      const ushort* bp = Wp + ((size_t)((kk * 8 + nf) * 2) * 64 + lane) * 8;
      const short8v bh = *(const short8v*)bp;
      const short8v bl = *(const short8v*)(bp + 512);
      accv[nf] = __builtin_amdgcn_mfma_f32_16x16x32_bf16(ah, bh, accv[nf], 0, 0, 0);
      accv[nf] = __builtin_amdgcn_mfma_f32_16x16x32_bf16(al, bh, accv[nf], 0, 0, 0);
      accv[nf] = __builtin_amdgcn_mfma_f32_16x16x32_bf16(ah, bl, accv[nf], 0, 0, 0);
    }
  }

  // ================= epilogue: regs -> LDS transpose -> coalesced stores ====
  const int colb = lane & 15;
  float bias8[8], g8[8], q8[8];
#pragma unroll
  for (int nf = 0; nf < 8; ++nf) {
    bias8[nf] = bias[nf * 16 + colb];
    if (MODE == 1) { g8[nf] = lng[nf * 16 + colb]; q8[nf] = lnb[nf * 16 + colb]; }
  }

  uint* AHu = (uint*)AH;
  const int wbase = w * 1024;               // wave-private: 16 rows x 64 uints
  const bool evl = (colb & 1) == 0;
  const int cc = colb >> 1;
#pragma unroll
  for (int r = 0; r < 4; ++r) {
    float z[8];
    float s = 0.f, s2 = 0.f;
#pragma unroll
    for (int nf = 0; nf < 8; ++nf) {
      z[nf] = fmaxf(accv[nf][r] + bias8[nf], 0.f);
      s += z[nf];
      s2 += z[nf] * z[nf];
    }
    if (MODE == 1) {
#pragma unroll
      for (int o = 1; o < 16; o <<= 1) { s += __shfl_xor(s, o); s2 += __shfl_xor(s2, o); }
      const float mu = s * (1.f / DD);
      const float inv = rsqrtf(s2 * (1.f / DD) - mu * mu + LN_EPS);
#pragma unroll
      for (int nf = 0; nf < 8; ++nf) z[nf] = (z[nf] - mu) * inv * g8[nf] + q8[nf];
    }
    // pack bf16 pairs: TWO lane-uniform shuffles per j (fixes R9 bug —
    // even lanes need partner's z[j], odd lanes need partner's z[j+4])
    const int row_local = (lane >> 4) * 4 + r;
    const int swz = (((row_local & 3) ^ (row_local >> 2)) & 3) << 3;
#pragma unroll
    for (int j = 0; j < 4; ++j) {
      const float p_lo = __shfl_xor(z[j], 1);      // partner's z[j]
      const float p_hi = __shfl_xor(z[j + 4], 1);  // partner's z[j+4]
      const uint pk = evl ? pack2(z[j], p_lo) : pack2(p_hi, z[j + 4]);
      const int ucol = (evl ? j * 8 : (j + 4) * 8) + cc;
      AHu[wbase + row_local * 64 + (ucol ^ swz)] = pk;
    }
  }
  // coalesced store: inst m covers 1 KB contiguous (4 rows x 256 B)
  const int lr = lane >> 4;          // row within group of 4
  const int lc = lane & 15;          // 16-B chunk
#pragma unroll
  for (int m = 0; m < 4; ++m) {
    const int row_local = lr + 4 * m;
    const int swz = (((row_local & 3) ^ (row_local >> 2)) & 3) << 3;
    const int grow = r0 + w * 16 + row_local;
    if (grow < NN) {
      const uint4 vv = *(const uint4*)&AHu[wbase + row_local * 64 + ((lc * 4) ^ swz)];
      *(uint4*)(Hout + grow * DD + lc * 8) = vv;
    }
  }
}

// ============ pool (bf16 h, batch_ids sorted; 64 threads, uint loads) ============
__global__ __launch_bounds__(64)
void pool_kernel(const ushort* __restrict__ h, const int* __restrict__ batch,
                 float* __restrict__ sums, float* __restrict__ counts) {
  const int c = threadIdx.x;                 // uint index: cols 2c, 2c+1
  const int base = blockIdx.x * 64;
  const int end = (base + 64 < NN) ? base + 64 : NN;
  const uint* __restrict__ hu = (const uint*)h;
  int cur = batch[base];
  float a0 = 0.f, a1 = 0.f, cnt = 0.f;
  for (int r = base; r < end; ++r) {
    const int g = batch[r];
    if (g != cur) {
      __hip_atomic_fetch_add(&sums[cur * DD + 2 * c], a0, __ATOMIC_RELAXED, __HIP_MEMORY_SCOPE_AGENT);
      __hip_atomic_fetch_add(&sums[cur * DD + 2 * c + 1], a1, __ATOMIC_RELAXED, __HIP_MEMORY_SCOPE_AGENT);
      if (c == 0)
        __hip_atomic_fetch_add(&counts[cur], cnt, __ATOMIC_RELAXED, __HIP_MEMORY_SCOPE_AGENT);
      a0 = 0.f; a1 = 0.f; cnt = 0.f; cur = g;
    }
    const float2 f = unpk2(hu[r * 64 + c]);
    a0 += f.x; a1 += f.y; cnt += 1.f;
  }
  __hip_atomic_fetch_add(&sums[cur * DD + 2 * c], a0, __ATOMIC_RELAXED, __HIP_MEMORY_SCOPE_AGENT);
  __hip_atomic_fetch_add(&sums[cur * DD + 2 * c + 1], a1, __ATOMIC_RELAXED, __HIP_MEMORY_SCOPE_AGENT);
  if (c == 0)
    __hip_atomic_fetch_add(&counts[cur], cnt, __ATOMIC_RELAXED, __HIP_MEMORY_SCOPE_AGENT);
}

__global__ __launch_bounds__(256)
void finalize_kernel(const float* __restrict__ sums, const float* __restrict__ counts,
                     float* __restrict__ out) {
  const int i = blockIdx.x * 256 + threadIdx.x;
  if (i >= NG * DD) return;
  out[i] = sums[i] / fmaxf(counts[i >> 7], 1.f);
}

extern "C" void kernel_launch(void* const* d_in, const int* in_sizes, int n_in,
                              void* d_out, int out_size, void* d_ws, size_t ws_size,
                              hipStream_t stream) {
  const float* x     = (const float*)d_in[0];
  const int*   ei    = (const int*)d_in[1];
  const int*   batch = (const int*)d_in[2];
  const float* projW = (const float*)d_in[3];
  const float* projb = (const float*)d_in[4];
  const float* mlpW  = (const float*)d_in[5];
  const float* mlpb  = (const float*)d_in[6];
  const float* lng   = (const float*)d_in[7];
  const float* lnb   = (const float*)d_in[8];
  float* out = (float*)d_out;

  char* ws = (char*)d_ws;
  ushort* hA    = (ushort*)(ws + 0);           // (NN+1)*256 B = 25,600,256
  ushort* hB    = (ushort*)(ws + 25600256);    // 25,600,256 B
  int*   csr    = (int*)   (ws + 51200512);    //  2,400,000 B
  int*   deg    = (int*)   (ws + 53600512);    //    400,000 B
  int*   off    = (int*)   (ws + 54000512);    //    400,000 B
  int*   btot   = (int*)   (ws + 54400512);    //        512 B
  ushort* Wp    = (ushort*)(ws + 54401024);    //    262,144 B
  float* sums   = (float*) (ws + 54663168);    //     32,768 B
  float* counts = (float*) (ws + 54695936);    //        256 B

  const int* src = ei;
  const int* dst = ei + NE;

  // zero rows (index NN) for the gather zero-target
  hipMemsetAsync(hA + (size_t)NN * DD, 0, DD * sizeof(ushort), stream);
  hipMemsetAsync(hB + (size_t)NN * DD, 0, DD * sizeof(ushort), stream);

  // ---- CSR build ----
  hipMemsetAsync(deg, 0, NN * sizeof(int), stream);
  count_kernel<<<(NE + 255) / 256, 256, 0, stream>>>(dst, deg);
  scan_a<<<(NN + 1023) / 1024, 256, 0, stream>>>(deg, off, btot);
  scan_b<<<1, 128, 0, stream>>>(btot, (NN + 1023) / 1024);
  scan_c<<<(NN + 255) / 256, 256, 0, stream>>>(off, btot);
  fill_kernel<<<(NE + 255) / 256, 256, 0, stream>>>(src, dst, off, csr);

  // ---- weight prep ----
  wprep_kernel<<<32, 256, 0, stream>>>(projW, mlpW, Wp);

  const int gemm_blocks = (NN + 63) / 64;   // 1563

  // h = relu(x @ projW + projb) -> bf16
  gemm_node<0><<<gemm_blocks, 256, 0, stream>>>(
      x, nullptr, nullptr, nullptr, Wp, projb, nullptr, nullptr, hA);

  // 3 fused GIN layers, ping-pong hA/hB
  ushort* hin = hA;
  ushort* hout = hB;
  for (int l = 0; l < NL; ++l) {
    gemm_node<1><<<gemm_blocks, 256, 0, stream>>>(
        nullptr, hin, csr, off, Wp + (size_t)(1 + l) * 32768,
        mlpb + (size_t)l * DD, lng + (size_t)l * DD, lnb + (size_t)l * DD, hout);
    ushort* tmp = hin; hin = hout; hout = tmp;
  }

  hipMemsetAsync(sums, 0, (size_t)(NG * DD + NG) * sizeof(float), stream);
  pool_kernel<<<(NN + 63) / 64, 64, 0, stream>>>(hin, batch, sums, counts);
  finalize_kernel<<<(NG * DD + 255) / 256, 256, 0, stream>>>(sums, counts, out);
}